// Round 4
// baseline (626.342 us; speedup 1.0000x reference)
//
#include <hip/hip_runtime.h>

// PointPillarScatter: scatter (B*P, C) pillar features into dense BEV canvas
// out[b][ch][y][x], zero elsewhere. B=8, C=64, NX=432, NY=496, NZ=1.
//
// Strategy: inverse map (pixel -> pillar) in d_ws, then ONE pass writes the
// 438.8 MB canvas exactly once, coalesced. Threads whose 4 pixels are all
// empty (~92%) take a branchless pure-store path (no loads, no waitcnts) --
// round-2 kernel was instruction/wait-bound (~3 TB/s), not BW-bound.

#define PPS_NX   432
#define PPS_NY   496
#define PPS_GRID (PPS_NX * PPS_NY)   // 214272, divisible by 4
#define PPS_C    64
#define PPS_B    8
#define PPS_U    (PPS_GRID / 4)      // 53568 float4-units per plane

// Native clang vector type: __builtin_nontemporal_store rejects HIP's
// float4 (HIP_vector_type class); ext_vector_type is accepted.
typedef float f32x4 __attribute__((ext_vector_type(4)));

// ---- Kernel 1: init inverse map to -1 (6.86 MB) -------------------------
__global__ void pps_init_map(int4* __restrict__ map4, int n4) {
    int i = blockIdx.x * blockDim.x + threadIdx.x;
    if (i < n4) map4[i] = make_int4(-1, -1, -1, -1);
}

// ---- Kernel 2: scatter pillar indices into the map (32768 x 4 B) --------
__global__ void pps_scatter_idx(const int4* __restrict__ coords,
                                int* __restrict__ map, int P) {
    int p = blockIdx.x * blockDim.x + threadIdx.x;
    if (p >= P) return;
    int4 c = coords[p];   // (batch, z, y, x)
    int pos = c.y + c.z * PPS_NX + c.w;           // in-plane index
    map[c.x * PPS_GRID + pos] = p;
}

// ---- Kernel 3: single-pass canvas write ---------------------------------
// Thread <-> (b, u): 4 consecutive pixels across all 64 channel planes.
// Wave store = 64 lanes x 16 B = 1 KB contiguous per plane (coalesced; same
// granularity as the 6.15 TB/s fill kernel).
// Fast path (all 4 pixels empty, ~92% of threads): pure nontemporal zero
// stores, no loads, no waitcnts inside the loop.
__global__ __launch_bounds__(256) void pps_gather(const float* __restrict__ pf,
                                                  const int* __restrict__ map,
                                                  float* __restrict__ out) {
    int t = blockIdx.x * blockDim.x + threadIdx.x;   // exact: 8*53568 = 1674*256
    int b = t / PPS_U;
    int u = t - b * PPS_U;

    const int4 m = ((const int4*)(map + (size_t)b * PPS_GRID))[u];
    float* ob = out + (size_t)b * ((size_t)PPS_C * PPS_GRID) + 4 * (size_t)u;

    const f32x4 z4 = {0.f, 0.f, 0.f, 0.f};

    // empty map entry == -1 (all bits set); pillar indices are >= 0, so
    // AND of the four has the sign bit set iff all four are empty.
    if ((m.x & m.y & m.z & m.w) < 0) {
        // ---- pure-zero path: 64 independent streaming stores ----
        #pragma unroll
        for (int ch = 0; ch < PPS_C; ++ch) {
            __builtin_nontemporal_store(z4, (f32x4*)(ob + (size_t)ch * PPS_GRID));
        }
    } else {
        // ---- compose path: gather pillar rows (4 ch at a time) ----
        #pragma unroll 2
        for (int ch0 = 0; ch0 < PPS_C; ch0 += 4) {
            f32x4 p0 = z4, p1 = z4, p2 = z4, p3 = z4;
            if (m.x >= 0) p0 = *(const f32x4*)(pf + (size_t)m.x * PPS_C + ch0);
            if (m.y >= 0) p1 = *(const f32x4*)(pf + (size_t)m.y * PPS_C + ch0);
            if (m.z >= 0) p2 = *(const f32x4*)(pf + (size_t)m.z * PPS_C + ch0);
            if (m.w >= 0) p3 = *(const f32x4*)(pf + (size_t)m.w * PPS_C + ch0);

            f32x4 r0 = {p0.x, p1.x, p2.x, p3.x};
            f32x4 r1 = {p0.y, p1.y, p2.y, p3.y};
            f32x4 r2 = {p0.z, p1.z, p2.z, p3.z};
            f32x4 r3 = {p0.w, p1.w, p2.w, p3.w};
            __builtin_nontemporal_store(r0, (f32x4*)(ob + (size_t)(ch0 + 0) * PPS_GRID));
            __builtin_nontemporal_store(r1, (f32x4*)(ob + (size_t)(ch0 + 1) * PPS_GRID));
            __builtin_nontemporal_store(r2, (f32x4*)(ob + (size_t)(ch0 + 2) * PPS_GRID));
            __builtin_nontemporal_store(r3, (f32x4*)(ob + (size_t)(ch0 + 3) * PPS_GRID));
        }
    }
}

// ---- Fallback (ws too small): zero + direct scatter ---------------------
__global__ void pps_zero_out(float4* __restrict__ out, long long n4) {
    long long i = (long long)blockIdx.x * blockDim.x + threadIdx.x;
    const long long stride = (long long)gridDim.x * blockDim.x;
    const float4 z = make_float4(0.f, 0.f, 0.f, 0.f);
    for (; i < n4; i += stride) out[i] = z;
}
__global__ void pps_scatter_feat(const float* __restrict__ pf,
                                 const int4* __restrict__ coords,
                                 float* __restrict__ out, int P) {
    int t = blockIdx.x * blockDim.x + threadIdx.x;
    int p = t >> 6;
    if (p >= P) return;
    int ch = t & 63;
    int4 c = coords[p];
    long long pos = (long long)c.x * (long long)(PPS_C * PPS_GRID)
                  + (long long)ch * PPS_GRID
                  + (long long)(c.y + c.z * PPS_NX + c.w);
    out[pos] = pf[t];
}

extern "C" void kernel_launch(void* const* d_in, const int* in_sizes, int n_in,
                              void* d_out, int out_size, void* d_ws, size_t ws_size,
                              hipStream_t stream) {
    const float* pf     = (const float*)d_in[0];
    const int4*  coords = (const int4*)d_in[1];
    float*       out    = (float*)d_out;
    int P = in_sizes[0] / PPS_C;   // B * P_PER = 32768

    const size_t map_bytes = (size_t)PPS_B * PPS_GRID * sizeof(int);
    if (ws_size >= map_bytes) {
        int* map = (int*)d_ws;
        int n4 = PPS_B * PPS_U;                       // 428544 int4 entries
        pps_init_map<<<(n4 + 255) / 256, 256, 0, stream>>>((int4*)map, n4);
        pps_scatter_idx<<<(P + 255) / 256, 256, 0, stream>>>(coords, map, P);
        pps_gather<<<PPS_B * PPS_U / 256, 256, 0, stream>>>(pf, map, out);
    } else {
        long long n4 = (long long)out_size / 4;
        pps_zero_out<<<2048, 256, 0, stream>>>((float4*)out, n4);
        int threads = P * PPS_C;
        pps_scatter_feat<<<(threads + 255) / 256, 256, 0, stream>>>(pf, coords, out, P);
    }
}

// Round 5
// 435.931 us; speedup vs baseline: 1.4368x; 1.4368x over previous
//
#include <hip/hip_runtime.h>

// PointPillarScatter: scatter (B*P, C) pillar features into dense BEV canvas
// out[b][ch][y][x], zero elsewhere. B=8, C=64, NX=432, NY=496, NZ=1.
//
// Strategy: inverse map (pixel -> pillar) in d_ws, then ONE output-linear
// pass: thread <-> one float4 of the canvas, consecutive threads write
// consecutive addresses chip-wide (identical pattern to the 6.15 TB/s fill
// kernel). Map int4 reads are coalesced and L2/L3-resident; ~93% of lanes
// store pure zeros, occupied lanes gather <=4 scalar pf values.
// Plain stores only: round 4 proved nontemporal stores drop write BW to
// 1.8 TB/s on gfx950 (L2 write-combining bypass).

#define PPS_NX   432
#define PPS_NY   496
#define PPS_GRID (PPS_NX * PPS_NY)   // 214272, divisible by 4
#define PPS_C    64
#define PPS_B    8
#define PPS_U    (PPS_GRID / 4)      // 53568 float4-units per plane

typedef float f32x4 __attribute__((ext_vector_type(4)));

// ---- Kernel 1: init inverse map to -1 (6.86 MB) -------------------------
__global__ void pps_init_map(int4* __restrict__ map4, int n4) {
    int i = blockIdx.x * blockDim.x + threadIdx.x;
    if (i < n4) map4[i] = make_int4(-1, -1, -1, -1);
}

// ---- Kernel 2: scatter pillar indices into the map (32768 x 4 B) --------
__global__ void pps_scatter_idx(const int4* __restrict__ coords,
                                int* __restrict__ map, int P) {
    int p = blockIdx.x * blockDim.x + threadIdx.x;
    if (p >= P) return;
    int4 c = coords[p];   // (batch, z, y, x)
    int pos = c.y + c.z * PPS_NX + c.w;           // in-plane index
    map[c.x * PPS_GRID + pos] = p;
}

// ---- Kernel 3: output-linear canvas write -------------------------------
// f = global float4 index into out (exact grid: 27,426,816 = 107,136 x 256).
// plane = b*64+ch, u = float4 index within the plane. Map entry (b,u) is
// shared by 64 planes -> L2/L3 hit after first touch. Write stream is
// globally contiguous -> HBM row-friendly like the fill kernel.
__global__ __launch_bounds__(256) void pps_write(const float* __restrict__ pf,
                                                 const int* __restrict__ map,
                                                 f32x4* __restrict__ out4) {
    int f = blockIdx.x * 256 + threadIdx.x;
    int plane = (unsigned)f / PPS_U;              // magic-mul division
    int u = f - plane * PPS_U;
    int b = plane >> 6;
    int ch = plane & 63;

    const int4 m = ((const int4*)(map + (size_t)b * PPS_GRID))[u];

    f32x4 v = {0.f, 0.f, 0.f, 0.f};
    // empty entry == -1; AND < 0 iff all four pixels empty (~93% of lanes)
    if ((m.x & m.y & m.z & m.w) >= 0) {
        if (m.x >= 0) v.x = pf[(size_t)m.x * PPS_C + ch];
        if (m.y >= 0) v.y = pf[(size_t)m.y * PPS_C + ch];
        if (m.z >= 0) v.z = pf[(size_t)m.z * PPS_C + ch];
        if (m.w >= 0) v.w = pf[(size_t)m.w * PPS_C + ch];
    }
    out4[f] = v;   // plain store: keep L2 write-combining
}

// ---- Fallback (ws too small): zero + direct scatter ---------------------
__global__ void pps_zero_out(float4* __restrict__ out, long long n4) {
    long long i = (long long)blockIdx.x * blockDim.x + threadIdx.x;
    const long long stride = (long long)gridDim.x * blockDim.x;
    const float4 z = make_float4(0.f, 0.f, 0.f, 0.f);
    for (; i < n4; i += stride) out[i] = z;
}
__global__ void pps_scatter_feat(const float* __restrict__ pf,
                                 const int4* __restrict__ coords,
                                 float* __restrict__ out, int P) {
    int t = blockIdx.x * blockDim.x + threadIdx.x;
    int p = t >> 6;
    if (p >= P) return;
    int ch = t & 63;
    int4 c = coords[p];
    long long pos = (long long)c.x * (long long)(PPS_C * PPS_GRID)
                  + (long long)ch * PPS_GRID
                  + (long long)(c.y + c.z * PPS_NX + c.w);
    out[pos] = pf[t];
}

extern "C" void kernel_launch(void* const* d_in, const int* in_sizes, int n_in,
                              void* d_out, int out_size, void* d_ws, size_t ws_size,
                              hipStream_t stream) {
    const float* pf     = (const float*)d_in[0];
    const int4*  coords = (const int4*)d_in[1];
    float*       out    = (float*)d_out;
    int P = in_sizes[0] / PPS_C;   // B * P_PER = 32768

    const size_t map_bytes = (size_t)PPS_B * PPS_GRID * sizeof(int);
    if (ws_size >= map_bytes) {
        int* map = (int*)d_ws;
        int n4 = PPS_B * PPS_U;                       // 428544 int4 entries
        pps_init_map<<<(n4 + 255) / 256, 256, 0, stream>>>((int4*)map, n4);
        pps_scatter_idx<<<(P + 255) / 256, 256, 0, stream>>>(coords, map, P);
        int total4 = out_size / 4;                    // 27,426,816
        pps_write<<<total4 / 256, 256, 0, stream>>>(pf, map, (f32x4*)out);
    } else {
        long long n4 = (long long)out_size / 4;
        pps_zero_out<<<2048, 256, 0, stream>>>((float4*)out, n4);
        int threads = P * PPS_C;
        pps_scatter_feat<<<(threads + 255) / 256, 256, 0, stream>>>(pf, coords, out, P);
    }
}